// Round 4
// baseline (1118.812 us; speedup 1.0000x reference)
//
#include <hip/hip_runtime.h>
#include <hip/hip_bf16.h>

typedef __hip_bfloat16 bf16;
typedef short v8s __attribute__((ext_vector_type(8)));
typedef float v4f __attribute__((ext_vector_type(4)));

#define BFLO(u) __uint_as_float((u) << 16)
#define BFHI(u) __uint_as_float((u) & 0xffff0000u)

#define CH 8192        // edges per count/distribute block
#define MAXNB 1600     // >= 2 * ceil(N/128) = 1564

// ---------------- index dtype detection ----------------
// int64 little-endian with values < 2^31: every odd int32 slot is a zero high
// word. Real int32 data: odd slots are node ids, nonzero w.h.p.
__global__ void detect_kernel(const int* __restrict__ e0, int* __restrict__ flag, int E) {
    __shared__ int sm;
    int t = threadIdx.x;
    if (t == 0) sm = 0;
    __syncthreads();
    int nz = 0;
    for (int i = t; i < 2048; i += 256) {
        int slot = 2 * i + 1;
        if (slot < 2 * E) nz |= (e0[slot] != 0);
    }
    if (nz) atomicOr(&sm, 1);
    __syncthreads();
    if (t == 0) *flag = sm ? 1 : 2;
}

// ---------------- x (fp32) -> Abig cols 256:383 (bf16) ----------------
// Abig row = 384 bf16 = 96 uint2. x portion starts at uint2 index 64.
__global__ void cvt_kernel(const float4* __restrict__ x4, uint2* __restrict__ Ab, int N) {
    int i = blockIdx.x * 256 + threadIdx.x;   // over N*32 groups of 4 floats
    if (i >= N * 32) return;
    int n = i >> 5, g = i & 31;
    float4 f = x4[i];
    union { uint2 u; bf16 h[4]; } o;
    o.h[0] = __float2bfloat16(f.x); o.h[1] = __float2bfloat16(f.y);
    o.h[2] = __float2bfloat16(f.z); o.h[3] = __float2bfloat16(f.w);
    Ab[(size_t)n * 96 + 64 + g] = o.u;
}

// ---------------- bucket count: bucket = r*nbr + (tgt>>7) ----------------

__global__ __launch_bounds__(256) void count_kernel(const int* __restrict__ e0,
                                                    const int* __restrict__ e1,
                                                    const int* __restrict__ flag,
                                                    int* __restrict__ gcnt, int E, int nbr) {
    __shared__ int hist[MAXNB];
    int NB = 2 * nbr;
    int t = threadIdx.x;
    for (int i = t; i < NB; i += 256) hist[i] = 0;
    __syncthreads();
    int st = *flag;
    long base = (long)blockIdx.x * CH;
#pragma unroll
    for (int j = 0; j < CH / 256; ++j) {
        long e = base + j * 256 + t;
        if (e < 2 * (long)E) {
            int r = e >= E;
            long idx = r ? e - E : e;
            int tgt = (r ? e1 : e0)[(size_t)(E + idx) * st];
            atomicAdd(&hist[r * nbr + (tgt >> 7)], 1);
        }
    }
    __syncthreads();
    for (int i = t; i < NB; i += 256) if (hist[i]) atomicAdd(&gcnt[i], hist[i]);
}

// ---------------- exclusive scan of bucket counts (single block) ----------------

__global__ __launch_bounds__(256) void bscan_kernel(const int* __restrict__ gcnt,
                                                    int* __restrict__ gbase,
                                                    int* __restrict__ gcur, int NB) {
    __shared__ int tsum[256];
    int t = threadIdx.x;
    int v[7]; int s = 0;
#pragma unroll
    for (int j = 0; j < 7; ++j) { int i = t * 7 + j; v[j] = (i < NB) ? gcnt[i] : 0; s += v[j]; }
    tsum[t] = s; __syncthreads();
    for (int d = 1; d < 256; d <<= 1) {
        int add = (t >= d) ? tsum[t - d] : 0;
        __syncthreads(); tsum[t] += add; __syncthreads();
    }
    int run = tsum[t] - s;
#pragma unroll
    for (int j = 0; j < 7; ++j) {
        int i = t * 7 + j;
        if (i < NB) { gbase[i] = run; gcur[i] = run; run += v[j]; }
    }
    if (t == 255) gbase[NB] = run;
}

// ---------------- distribute: LDS-sorted runs -> contiguous bucket segments ----------------
// record = src (17b) | tgt_local (7b) << 17

__global__ __launch_bounds__(256) void dist_kernel(const int* __restrict__ e0,
                                                   const int* __restrict__ e1,
                                                   const int* __restrict__ flag,
                                                   int* __restrict__ gcur,
                                                   unsigned int* __restrict__ esorted,
                                                   int E, int nbr) {
    __shared__ int hist[MAXNB], lstart[MAXNB], lcur[MAXNB], runbase[MAXNB];
    __shared__ unsigned int ordered[CH];
    __shared__ int tsum[256];
    int NB = 2 * nbr;
    int t = threadIdx.x;
    for (int i = t; i < NB; i += 256) { hist[i] = 0; lcur[i] = 0; }
    __syncthreads();
    int st = *flag;
    long base = (long)blockIdx.x * CH;
    unsigned int rec[CH / 256]; int bk[CH / 256];
#pragma unroll
    for (int j = 0; j < CH / 256; ++j) {
        long e = base + j * 256 + t;
        if (e < 2 * (long)E) {
            int r = e >= E;
            long idx = r ? e - E : e;
            const int* ei = r ? e1 : e0;
            int src = ei[(size_t)idx * st];
            int tgt = ei[(size_t)(E + idx) * st];
            bk[j] = r * nbr + (tgt >> 7);
            rec[j] = (unsigned int)src | ((unsigned int)(tgt & 127) << 17);
            atomicAdd(&hist[bk[j]], 1);
        } else bk[j] = -1;
    }
    __syncthreads();
    {   // block-level exclusive scan of hist -> lstart
        int vv[7]; int s = 0;
#pragma unroll
        for (int j = 0; j < 7; ++j) { int i = t * 7 + j; vv[j] = (i < NB) ? hist[i] : 0; s += vv[j]; }
        tsum[t] = s; __syncthreads();
        for (int d = 1; d < 256; d <<= 1) {
            int add = (t >= d) ? tsum[t - d] : 0;
            __syncthreads(); tsum[t] += add; __syncthreads();
        }
        int run = tsum[t] - s;
#pragma unroll
        for (int j = 0; j < 7; ++j) { int i = t * 7 + j; if (i < NB) { lstart[i] = run; run += vv[j]; } }
    }
    __syncthreads();
    // reserve global run per touched bucket
    for (int i = t; i < NB; i += 256) if (hist[i]) runbase[i] = atomicAdd(&gcur[i], hist[i]);
    __syncthreads();
    // scatter records into bucket-ordered staging
#pragma unroll
    for (int j = 0; j < CH / 256; ++j) if (bk[j] >= 0) {
        int p = lstart[bk[j]] + atomicAdd(&lcur[bk[j]], 1);
        ordered[p] = rec[j];
    }
    __syncthreads();
    // copy runs to global (contiguous per bucket)
    for (int b = t; b < NB; b += 256) {
        int n = hist[b];
        if (n) {
            int gp = runbase[b], lp = lstart[b];
            for (int q = 0; q < n; ++q) esorted[gp + q] = ordered[lp + q];
        }
    }
}

// ---------------- accumulate: one block per bucket, 128-node fp32 LDS window ----------------

__global__ __launch_bounds__(256) void acc_kernel(const unsigned int* __restrict__ esorted,
                                                  const int* __restrict__ gbase,
                                                  const uint2* __restrict__ Ab,
                                                  uint2* __restrict__ AbH,
                                                  int N, int nbr) {
    __shared__ float acc[128 * 128];   // 64 KB
    int t = threadIdx.x;
    int b = blockIdx.x;
    int r = b >= nbr;
    int g = r ? b - nbr : b;
    for (int i = t; i < 128 * 32; i += 256) *(float4*)&acc[i * 4] = float4{0.f, 0.f, 0.f, 0.f};
    __syncthreads();
    int s0 = gbase[b], s1 = gbase[b + 1];
    int cnt = s1 - s0;
    int lane = t & 63, w = t >> 6, half = lane >> 5, lj = lane & 31;
    int rot = (lj >> 3) & 3;
    for (int base2 = 0; base2 < cnt; base2 += 64) {
        unsigned int recs[8]; uint2 v[8];
#pragma unroll
        for (int u = 0; u < 8; ++u) {
            int i = base2 + w * 16 + u * 2 + half;
            int ic = (i < cnt) ? i : (cnt - 1);
            recs[u] = esorted[s0 + ic];
        }
#pragma unroll
        for (int u = 0; u < 8; ++u) {
            int src = recs[u] & 0x1FFFF;
            v[u] = Ab[(size_t)src * 96 + 64 + lj];
        }
#pragma unroll
        for (int u = 0; u < 8; ++u) {
            int i = base2 + w * 16 + u * 2 + half;
            if (i < cnt) {
                int tl = (recs[u] >> 17) & 127;
                float vals[4] = { BFLO(v[u].x), BFHI(v[u].x), BFLO(v[u].y), BFHI(v[u].y) };
                float* rowp = &acc[tl * 128 + lj * 4];
#pragma unroll
                for (int s = 0; s < 4; ++s) {     // bank-rotated k-order: conflict-free
                    int k = (rot + s) & 3;
                    atomicAdd(&rowp[k], vals[k]);
                }
            }
        }
    }
    __syncthreads();
    // writeback window -> Ab H-region (cols r*64.. as uint2 lanes r*32..)
    for (int i = t; i < 128 * 32; i += 256) {
        int row = i >> 5, c8 = i & 31;
        int n = g * 128 + row;
        if (n < N) {
            float4 f = *(float4*)&acc[row * 128 + c8 * 4];
            union { uint2 u; bf16 h[4]; } o;
            o.h[0] = __float2bfloat16(f.x); o.h[1] = __float2bfloat16(f.y);
            o.h[2] = __float2bfloat16(f.z); o.h[3] = __float2bfloat16(f.w);
            AbH[(size_t)n * 96 + r * 32 + c8] = o.u;
        }
    }
}

// ---------------- weight prep (fp32 -> bf16) ----------------

__global__ void prep_kernel(const float* __restrict__ Wrel, const float* __restrict__ Wself,
                            const float* __restrict__ convw, const float* __restrict__ convb,
                            bf16* __restrict__ B1T, bf16* __restrict__ B2T, float* __restrict__ cbf) {
    int i = blockIdx.x * 256 + threadIdx.x;
    if (i < 49152) {
        int co = i / 384, k = i % 384;
        float v;
        if (k < 128)      v = Wrel[co * 128 + k];
        else if (k < 256) v = Wrel[16384 + co * 128 + (k - 128)];
        else              v = Wself[co * 128 + (k - 256)];
        B1T[i] = __float2bfloat16(v);
    } else if (i < 98304) {
        int j = i - 49152;
        int co = j / 384, k = j % 384, kk = k >> 7, ci = k & 127;
        B2T[j] = __float2bfloat16(convw[co * 384 + ci * 3 + kk]);
    } else if (i < 98432) {
        int c = i - 98304;
        cbf[c] = convb[c];
    }
}

// ---------------- GEMM1: agg[M,128](bf16) = Abig @ B1T^T,  K = 384 ----------------

__global__ __launch_bounds__(256) void gemm1_kernel(const bf16* __restrict__ Ab,
                                                    const bf16* __restrict__ B1T,
                                                    bf16* __restrict__ agg, int M) {
    __shared__ bf16 Al[128 * 72];
    __shared__ bf16 Bl[128 * 72];
    int t = threadIdx.x;
    int lane = t & 63, wv = t >> 6, wm = wv >> 1, wn = wv & 1;
    int m0 = blockIdx.x * 128;
    v4f acc[4][4] = {};
    for (int kt = 0; kt < 6; ++kt) {
        int k0 = kt * 64;
#pragma unroll
        for (int i = 0; i < 4; ++i) {
            int q = i * 256 + t;
            int row = q >> 3, ch = q & 7;
            int grow = m0 + row;
            int4 va = {0, 0, 0, 0};
            if (grow < M) va = *(const int4*)(Ab + (size_t)grow * 384 + k0 + ch * 8);
            *(int4*)&Al[row * 72 + ch * 8] = va;
            *(int4*)&Bl[row * 72 + ch * 8] = *(const int4*)(B1T + row * 384 + k0 + ch * 8);
        }
        __syncthreads();
        int r = lane & 15, qq = lane >> 4;
#pragma unroll
        for (int ks = 0; ks < 2; ++ks) {
            v8s af[4], bfr[4];
#pragma unroll
            for (int tm = 0; tm < 4; ++tm)
                af[tm] = *(const v8s*)&Al[(wm * 64 + tm * 16 + r) * 72 + ks * 32 + qq * 8];
#pragma unroll
            for (int tn = 0; tn < 4; ++tn)
                bfr[tn] = *(const v8s*)&Bl[(wn * 64 + tn * 16 + r) * 72 + ks * 32 + qq * 8];
#pragma unroll
            for (int tm = 0; tm < 4; ++tm)
#pragma unroll
                for (int tn = 0; tn < 4; ++tn)
                    acc[tm][tn] = __builtin_amdgcn_mfma_f32_16x16x32_bf16(af[tm], bfr[tn], acc[tm][tn], 0, 0, 0);
        }
        __syncthreads();
    }
    int r = lane & 15, qq = lane >> 4;
#pragma unroll
    for (int tm = 0; tm < 4; ++tm)
#pragma unroll
        for (int tn = 0; tn < 4; ++tn)
#pragma unroll
            for (int reg = 0; reg < 4; ++reg) {
                int grow = m0 + wm * 64 + tm * 16 + qq * 4 + reg;
                if (grow < M) {
                    int col = wn * 64 + tn * 16 + r;
                    agg[(size_t)grow * 128 + col] = __float2bfloat16(acc[tm][tn][reg]);
                }
            }
}

// ---------------- GEMM2: out[n](fp32) = relu(b + sum_kk agg[n+kk-1] @ Wkk^T),  K = 384 ----------------

__global__ __launch_bounds__(256) void gemm2_kernel(const bf16* __restrict__ agg,
                                                    const bf16* __restrict__ B2T,
                                                    const float* __restrict__ cbf,
                                                    float* __restrict__ out, int M) {
    __shared__ bf16 Al[128 * 72];
    __shared__ bf16 Bl[128 * 72];
    int t = threadIdx.x;
    int lane = t & 63, wv = t >> 6, wm = wv >> 1, wn = wv & 1;
    int m0 = blockIdx.x * 128;
    v4f acc[4][4] = {};
    for (int kt = 0; kt < 6; ++kt) {
        int k0 = kt * 64;
        int kk = k0 >> 7;          // which conv tap (0..2)
        int rem = k0 & 127;        // ci offset within tap
#pragma unroll
        for (int i = 0; i < 4; ++i) {
            int q = i * 256 + t;
            int row = q >> 3, ch = q & 7;
            int srow = m0 + row + kk - 1;
            int4 va = {0, 0, 0, 0};
            if (srow >= 0 && srow < M) {
                va = *(const int4*)(agg + (size_t)srow * 128 + rem + ch * 8);
            }
            *(int4*)&Al[row * 72 + ch * 8] = va;
            *(int4*)&Bl[row * 72 + ch * 8] = *(const int4*)(B2T + row * 384 + k0 + ch * 8);
        }
        __syncthreads();
        int r = lane & 15, qq = lane >> 4;
#pragma unroll
        for (int ks = 0; ks < 2; ++ks) {
            v8s af[4], bfr[4];
#pragma unroll
            for (int tm = 0; tm < 4; ++tm)
                af[tm] = *(const v8s*)&Al[(wm * 64 + tm * 16 + r) * 72 + ks * 32 + qq * 8];
#pragma unroll
            for (int tn = 0; tn < 4; ++tn)
                bfr[tn] = *(const v8s*)&Bl[(wn * 64 + tn * 16 + r) * 72 + ks * 32 + qq * 8];
#pragma unroll
            for (int tm = 0; tm < 4; ++tm)
#pragma unroll
                for (int tn = 0; tn < 4; ++tn)
                    acc[tm][tn] = __builtin_amdgcn_mfma_f32_16x16x32_bf16(af[tm], bfr[tn], acc[tm][tn], 0, 0, 0);
        }
        __syncthreads();
    }
    int r = lane & 15, qq = lane >> 4;
#pragma unroll
    for (int tm = 0; tm < 4; ++tm)
#pragma unroll
        for (int tn = 0; tn < 4; ++tn) {
            int col = wn * 64 + tn * 16 + r;
            float bias = cbf[col];
#pragma unroll
            for (int reg = 0; reg < 4; ++reg) {
                int grow = m0 + wm * 64 + tm * 16 + qq * 4 + reg;
                if (grow < M) {
                    float v = acc[tm][tn][reg] + bias;
                    out[(size_t)grow * 128 + col] = fmaxf(v, 0.f);
                }
            }
        }
}

// ---------------- launch ----------------

extern "C" void kernel_launch(void* const* d_in, const int* in_sizes, int n_in,
                              void* d_out, int out_size, void* d_ws, size_t ws_size,
                              hipStream_t stream) {
    const float* x     = (const float*)d_in[0];
    const int*   e0    = (const int*)d_in[1];
    const int*   e1    = (const int*)d_in[2];
    const float* Wrel  = (const float*)d_in[3];
    const float* Wself = (const float*)d_in[4];
    const float* convw = (const float*)d_in[5];
    const float* convb = (const float*)d_in[6];
    float* out = (float*)d_out;

    int N = in_sizes[0] / 128;   // 100000
    int E = in_sizes[1] / 2;     // 600000
    int nbr = (N + 127) >> 7;    // 782 buckets per relation
    int NB = 2 * nbr;            // 1564

    char* p = (char*)d_ws;
    auto alloc = [&](size_t bytes) { char* q = p; p += (bytes + 255) & ~(size_t)255; return q; };
    int*  gcnt  = (int*)alloc((size_t)MAXNB * 4);
    int*  gbase = (int*)alloc((size_t)(MAXNB + 1) * 4);
    int*  gcur  = (int*)alloc((size_t)MAXNB * 4);
    int*  flag  = (int*)alloc(256);
    unsigned int* esorted = (unsigned int*)alloc((size_t)2 * E * 4);
    bf16* Ab   = (bf16*)alloc((size_t)N * 384 * 2);   // [H0 | H1 | x_bf16]
    bf16* agg  = (bf16*)alloc((size_t)N * 128 * 2);
    bf16* B1T  = (bf16*)alloc(384 * 128 * 2);
    bf16* B2T  = (bf16*)alloc(384 * 128 * 2);
    float* cbf = (float*)alloc(512);

    hipMemsetAsync(gcnt, 0, (size_t)NB * 4, stream);

    detect_kernel<<<1, 256, 0, stream>>>(e0, flag, E);

    cvt_kernel<<<(N * 32 + 255) / 256, 256, 0, stream>>>((const float4*)x, (uint2*)Ab, N);

    int chBlocks = (2 * E + CH - 1) / CH;    // 147
    count_kernel<<<chBlocks, 256, 0, stream>>>(e0, e1, flag, gcnt, E, nbr);
    bscan_kernel<<<1, 256, 0, stream>>>(gcnt, gbase, gcur, NB);
    dist_kernel<<<chBlocks, 256, 0, stream>>>(e0, e1, flag, gcur, esorted, E, nbr);

    acc_kernel<<<NB, 256, 0, stream>>>(esorted, gbase, (const uint2*)Ab, (uint2*)Ab, N, nbr);

    prep_kernel<<<(98432 + 255) / 256, 256, 0, stream>>>(Wrel, Wself, convw, convb, B1T, B2T, cbf);

    int mBlocks = (N + 127) / 128;
    gemm1_kernel<<<mBlocks, 256, 0, stream>>>(Ab, B1T, agg, N);
    gemm2_kernel<<<mBlocks, 256, 0, stream>>>(agg, B2T, cbf, out, N);
}

// Round 5
// 310.418 us; speedup vs baseline: 3.6042x; 3.6042x over previous
//
#include <hip/hip_runtime.h>
#include <hip/hip_bf16.h>

typedef __hip_bfloat16 bf16;
typedef short v8s __attribute__((ext_vector_type(8)));
typedef float v4f __attribute__((ext_vector_type(4)));

#define BFLO(u) __uint_as_float((u) << 16)
#define BFHI(u) __uint_as_float((u) & 0xffff0000u)

#define CH 8192        // edges per count/distribute block
#define MAXNB 800      // >= 2 * ceil(N/256) = 782

// ---------------- index dtype detection ----------------
// int64 little-endian with values < 2^31: every odd int32 slot is a zero high
// word. Real int32 data: odd slots are node ids, nonzero w.h.p.
__global__ void detect_kernel(const int* __restrict__ e0, int* __restrict__ flag, int E) {
    __shared__ int sm;
    int t = threadIdx.x;
    if (t == 0) sm = 0;
    __syncthreads();
    int nz = 0;
    for (int i = t; i < 2048; i += 256) {
        int slot = 2 * i + 1;
        if (slot < 2 * E) nz |= (e0[slot] != 0);
    }
    if (nz) atomicOr(&sm, 1);
    __syncthreads();
    if (t == 0) *flag = sm ? 1 : 2;
}

// ---------------- x (fp32) -> Abig cols 256:383 (bf16) ----------------
// Abig row = 384 bf16 = 96 uint2. x portion starts at uint2 index 64.
__global__ void cvt_kernel(const float4* __restrict__ x4, uint2* __restrict__ Ab, int N) {
    int i = blockIdx.x * 256 + threadIdx.x;   // over N*32 groups of 4 floats
    if (i >= N * 32) return;
    int n = i >> 5, g = i & 31;
    float4 f = x4[i];
    union { uint2 u; bf16 h[4]; } o;
    o.h[0] = __float2bfloat16(f.x); o.h[1] = __float2bfloat16(f.y);
    o.h[2] = __float2bfloat16(f.z); o.h[3] = __float2bfloat16(f.w);
    Ab[(size_t)n * 96 + 64 + g] = o.u;
}

// ---------------- bucket count: bucket = r*nbrr + (tgt>>8) ----------------

__global__ __launch_bounds__(256) void count_kernel(const int* __restrict__ e0,
                                                    const int* __restrict__ e1,
                                                    const int* __restrict__ flag,
                                                    int* __restrict__ gcnt, int E, int nbrr) {
    __shared__ int hist[MAXNB];
    int NB = 2 * nbrr;
    int t = threadIdx.x;
    for (int i = t; i < NB; i += 256) hist[i] = 0;
    __syncthreads();
    int st = *flag;
    long base = (long)blockIdx.x * CH;
#pragma unroll
    for (int j = 0; j < CH / 256; ++j) {
        long e = base + j * 256 + t;
        if (e < 2 * (long)E) {
            int r = e >= E;
            long idx = r ? e - E : e;
            int tgt = (r ? e1 : e0)[(size_t)(E + idx) * st];
            atomicAdd(&hist[r * nbrr + (tgt >> 8)], 1);
        }
    }
    __syncthreads();
    for (int i = t; i < NB; i += 256) if (hist[i]) atomicAdd(&gcnt[i], hist[i]);
}

// ---------------- exclusive scan of bucket counts (single block) ----------------

__global__ __launch_bounds__(256) void bscan_kernel(const int* __restrict__ gcnt,
                                                    int* __restrict__ gbase,
                                                    int* __restrict__ gcur, int NB) {
    __shared__ int tsum[256];
    int t = threadIdx.x;
    int v[4]; int s = 0;
#pragma unroll
    for (int j = 0; j < 4; ++j) { int i = t * 4 + j; v[j] = (i < NB) ? gcnt[i] : 0; s += v[j]; }
    tsum[t] = s; __syncthreads();
    for (int d = 1; d < 256; d <<= 1) {
        int add = (t >= d) ? tsum[t - d] : 0;
        __syncthreads(); tsum[t] += add; __syncthreads();
    }
    int run = tsum[t] - s;
#pragma unroll
    for (int j = 0; j < 4; ++j) {
        int i = t * 4 + j;
        if (i < NB) { gbase[i] = run; gcur[i] = run; }
        run += v[j];
    }
    if (t == 255) gbase[NB] = run;
}

// ---------------- distribute: LDS-sorted runs -> contiguous bucket segments ----------------
// record = src (17b) | tgt_local (8b) << 17

__global__ __launch_bounds__(256) void dist_kernel(const int* __restrict__ e0,
                                                   const int* __restrict__ e1,
                                                   const int* __restrict__ flag,
                                                   int* __restrict__ gcur,
                                                   unsigned int* __restrict__ esorted,
                                                   int E, int nbrr) {
    __shared__ int hist[MAXNB], lstart[MAXNB], lcur[MAXNB], runbase[MAXNB];
    __shared__ unsigned int ordered[CH];
    __shared__ int tsum[256];
    int NB = 2 * nbrr;
    int t = threadIdx.x;
    for (int i = t; i < NB; i += 256) { hist[i] = 0; lcur[i] = 0; }
    __syncthreads();
    int st = *flag;
    long base = (long)blockIdx.x * CH;
    unsigned int rec[CH / 256]; short bk[CH / 256];
#pragma unroll
    for (int j = 0; j < CH / 256; ++j) {
        long e = base + j * 256 + t;
        if (e < 2 * (long)E) {
            int r = e >= E;
            long idx = r ? e - E : e;
            const int* ei = r ? e1 : e0;
            int src = ei[(size_t)idx * st];
            int tgt = ei[(size_t)(E + idx) * st];
            bk[j] = (short)(r * nbrr + (tgt >> 8));
            rec[j] = (unsigned int)src | ((unsigned int)(tgt & 255) << 17);
            atomicAdd(&hist[bk[j]], 1);
        } else bk[j] = -1;
    }
    __syncthreads();
    {   // block-level exclusive scan of hist -> lstart
        int vv[4]; int s = 0;
#pragma unroll
        for (int j = 0; j < 4; ++j) { int i = t * 4 + j; vv[j] = (i < NB) ? hist[i] : 0; s += vv[j]; }
        tsum[t] = s; __syncthreads();
        for (int d = 1; d < 256; d <<= 1) {
            int add = (t >= d) ? tsum[t - d] : 0;
            __syncthreads(); tsum[t] += add; __syncthreads();
        }
        int run = tsum[t] - s;
#pragma unroll
        for (int j = 0; j < 4; ++j) { int i = t * 4 + j; if (i < NB) { lstart[i] = run; run += vv[j]; } }
    }
    __syncthreads();
    // reserve global run per touched bucket
    for (int i = t; i < NB; i += 256) if (hist[i]) runbase[i] = atomicAdd(&gcur[i], hist[i]);
    __syncthreads();
    // scatter records into bucket-ordered staging
#pragma unroll
    for (int j = 0; j < CH / 256; ++j) if (bk[j] >= 0) {
        int p = lstart[bk[j]] + atomicAdd(&lcur[bk[j]], 1);
        ordered[p] = rec[j];
    }
    __syncthreads();
    // copy runs to global (contiguous per bucket)
    for (int b = t; b < NB; b += 256) {
        int n = hist[b];
        if (n) {
            int gp = runbase[b], lp = lstart[b];
            for (int q = 0; q < n; ++q) esorted[gp + q] = ordered[lp + q];
        }
    }
}

// ---------------- per-node CSR within each bucket segment ----------------
// One block per bucket. All global writes stay inside the block's own
// contiguous segment (or its 1 KB off/cnt slice) -> no cross-XCD ping-pong.

__global__ __launch_bounds__(256) void csr_kernel(const unsigned int* __restrict__ esorted,
                                                  const int* __restrict__ gbase,
                                                  int* __restrict__ off, int* __restrict__ cnt,
                                                  int* __restrict__ esrc, int N, int nbrr) {
    __shared__ int hist[256], lcur[256], tsum[256];
    int b = blockIdx.x;
    int r = b >= nbrr;
    int g = r ? b - nbrr : b;
    int t = threadIdx.x;
    int s0 = gbase[b], s1 = gbase[b + 1];
    hist[t] = 0;
    __syncthreads();
    for (int i = s0 + t; i < s1; i += 256)
        atomicAdd(&hist[(esorted[i] >> 17) & 255], 1);
    __syncthreads();
    int h = hist[t];
    tsum[t] = h; __syncthreads();
    for (int d = 1; d < 256; d <<= 1) {
        int add = (t >= d) ? tsum[t - d] : 0;
        __syncthreads(); tsum[t] += add; __syncthreads();
    }
    int start = tsum[t] - h;   // exclusive
    int node = g * 256 + t;
    if (node < N) { off[r * N + node] = s0 + start; cnt[r * N + node] = h; }
    lcur[t] = start;
    __syncthreads();
    for (int i = s0 + t; i < s1; i += 256) {
        unsigned int rec = esorted[i];
        int tl = (rec >> 17) & 255;
        int p = atomicAdd(&lcur[tl], 1);
        esrc[s0 + p] = rec & 0x1FFFF;
    }
}

// ---------------- gather-reduce into Abig cols 0:255 ----------------
// One half-wave (32 lanes x 8B = 256B = one bf16 row) per (node, relation).
// Edge loop unrolled x4 with clamped indices (MLP).
__global__ __launch_bounds__(256) void gather_kernel(const int* __restrict__ off,
                                                     const int* __restrict__ cnt,
                                                     const int* __restrict__ esrc,
                                                     uint2* __restrict__ Ab, int N) {
    int hw = blockIdx.x * 8 + (threadIdx.x >> 5);
    int lane = threadIdx.x & 31;
    if (hw >= 2 * N) return;
    int r = (hw >= N);
    int n = r ? hw - N : hw;
    int s0 = off[hw], c = cnt[hw];
    float a0 = 0.f, a1 = 0.f, a2 = 0.f, a3 = 0.f;
    for (int i = 0; i < c; i += 4) {
        int cm1 = c - 1;
        int j1 = (i + 1 <= cm1) ? i + 1 : cm1;
        int j2 = (i + 2 <= cm1) ? i + 2 : cm1;
        int j3 = (i + 3 <= cm1) ? i + 3 : cm1;
        int sA = esrc[s0 + i];
        int sB = esrc[s0 + j1];
        int sC = esrc[s0 + j2];
        int sD = esrc[s0 + j3];
        uint2 vA = Ab[(size_t)sA * 96 + 64 + lane];
        uint2 vB = Ab[(size_t)sB * 96 + 64 + lane];
        uint2 vC = Ab[(size_t)sC * 96 + 64 + lane];
        uint2 vD = Ab[(size_t)sD * 96 + 64 + lane];
        a0 += BFLO(vA.x); a1 += BFHI(vA.x); a2 += BFLO(vA.y); a3 += BFHI(vA.y);
        if (i + 1 < c) { a0 += BFLO(vB.x); a1 += BFHI(vB.x); a2 += BFLO(vB.y); a3 += BFHI(vB.y); }
        if (i + 2 < c) { a0 += BFLO(vC.x); a1 += BFHI(vC.x); a2 += BFLO(vC.y); a3 += BFHI(vC.y); }
        if (i + 3 < c) { a0 += BFLO(vD.x); a1 += BFHI(vD.x); a2 += BFLO(vD.y); a3 += BFHI(vD.y); }
    }
    union { uint2 u; bf16 h[4]; } o;
    o.h[0] = __float2bfloat16(a0); o.h[1] = __float2bfloat16(a1);
    o.h[2] = __float2bfloat16(a2); o.h[3] = __float2bfloat16(a3);
    Ab[(size_t)n * 96 + (size_t)r * 32 + lane] = o.u;
}

// ---------------- weight prep (fp32 -> bf16) ----------------

__global__ void prep_kernel(const float* __restrict__ Wrel, const float* __restrict__ Wself,
                            const float* __restrict__ convw, const float* __restrict__ convb,
                            bf16* __restrict__ B1T, bf16* __restrict__ B2T, float* __restrict__ cbf) {
    int i = blockIdx.x * 256 + threadIdx.x;
    if (i < 49152) {
        int co = i / 384, k = i % 384;
        float v;
        if (k < 128)      v = Wrel[co * 128 + k];
        else if (k < 256) v = Wrel[16384 + co * 128 + (k - 128)];
        else              v = Wself[co * 128 + (k - 256)];
        B1T[i] = __float2bfloat16(v);
    } else if (i < 98304) {
        int j = i - 49152;
        int co = j / 384, k = j % 384, kk = k >> 7, ci = k & 127;
        B2T[j] = __float2bfloat16(convw[co * 384 + ci * 3 + kk]);
    } else if (i < 98432) {
        int c = i - 98304;
        cbf[c] = convb[c];
    }
}

// ---------------- GEMM1: agg[M,128](bf16) = Abig @ B1T^T,  K = 384 ----------------

__global__ __launch_bounds__(256) void gemm1_kernel(const bf16* __restrict__ Ab,
                                                    const bf16* __restrict__ B1T,
                                                    bf16* __restrict__ agg, int M) {
    __shared__ bf16 Al[128 * 72];
    __shared__ bf16 Bl[128 * 72];
    int t = threadIdx.x;
    int lane = t & 63, wv = t >> 6, wm = wv >> 1, wn = wv & 1;
    int m0 = blockIdx.x * 128;
    v4f acc[4][4] = {};
    for (int kt = 0; kt < 6; ++kt) {
        int k0 = kt * 64;
#pragma unroll
        for (int i = 0; i < 4; ++i) {
            int q = i * 256 + t;
            int row = q >> 3, ch = q & 7;
            int grow = m0 + row;
            int4 va = {0, 0, 0, 0};
            if (grow < M) va = *(const int4*)(Ab + (size_t)grow * 384 + k0 + ch * 8);
            *(int4*)&Al[row * 72 + ch * 8] = va;
            *(int4*)&Bl[row * 72 + ch * 8] = *(const int4*)(B1T + row * 384 + k0 + ch * 8);
        }
        __syncthreads();
        int r = lane & 15, qq = lane >> 4;
#pragma unroll
        for (int ks = 0; ks < 2; ++ks) {
            v8s af[4], bfr[4];
#pragma unroll
            for (int tm = 0; tm < 4; ++tm)
                af[tm] = *(const v8s*)&Al[(wm * 64 + tm * 16 + r) * 72 + ks * 32 + qq * 8];
#pragma unroll
            for (int tn = 0; tn < 4; ++tn)
                bfr[tn] = *(const v8s*)&Bl[(wn * 64 + tn * 16 + r) * 72 + ks * 32 + qq * 8];
#pragma unroll
            for (int tm = 0; tm < 4; ++tm)
#pragma unroll
                for (int tn = 0; tn < 4; ++tn)
                    acc[tm][tn] = __builtin_amdgcn_mfma_f32_16x16x32_bf16(af[tm], bfr[tn], acc[tm][tn], 0, 0, 0);
        }
        __syncthreads();
    }
    int r = lane & 15, qq = lane >> 4;
#pragma unroll
    for (int tm = 0; tm < 4; ++tm)
#pragma unroll
        for (int tn = 0; tn < 4; ++tn)
#pragma unroll
            for (int reg = 0; reg < 4; ++reg) {
                int grow = m0 + wm * 64 + tm * 16 + qq * 4 + reg;
                if (grow < M) {
                    int col = wn * 64 + tn * 16 + r;
                    agg[(size_t)grow * 128 + col] = __float2bfloat16(acc[tm][tn][reg]);
                }
            }
}

// ---------------- GEMM2: out[n](fp32) = relu(b + sum_kk agg[n+kk-1] @ Wkk^T),  K = 384 ----------------

__global__ __launch_bounds__(256) void gemm2_kernel(const bf16* __restrict__ agg,
                                                    const bf16* __restrict__ B2T,
                                                    const float* __restrict__ cbf,
                                                    float* __restrict__ out, int M) {
    __shared__ bf16 Al[128 * 72];
    __shared__ bf16 Bl[128 * 72];
    int t = threadIdx.x;
    int lane = t & 63, wv = t >> 6, wm = wv >> 1, wn = wv & 1;
    int m0 = blockIdx.x * 128;
    v4f acc[4][4] = {};
    for (int kt = 0; kt < 6; ++kt) {
        int k0 = kt * 64;
        int kk = k0 >> 7;          // which conv tap (0..2)
        int rem = k0 & 127;        // ci offset within tap
#pragma unroll
        for (int i = 0; i < 4; ++i) {
            int q = i * 256 + t;
            int row = q >> 3, ch = q & 7;
            int srow = m0 + row + kk - 1;
            int4 va = {0, 0, 0, 0};
            if (srow >= 0 && srow < M) {
                va = *(const int4*)(agg + (size_t)srow * 128 + rem + ch * 8);
            }
            *(int4*)&Al[row * 72 + ch * 8] = va;
            *(int4*)&Bl[row * 72 + ch * 8] = *(const int4*)(B2T + row * 384 + k0 + ch * 8);
        }
        __syncthreads();
        int r = lane & 15, qq = lane >> 4;
#pragma unroll
        for (int ks = 0; ks < 2; ++ks) {
            v8s af[4], bfr[4];
#pragma unroll
            for (int tm = 0; tm < 4; ++tm)
                af[tm] = *(const v8s*)&Al[(wm * 64 + tm * 16 + r) * 72 + ks * 32 + qq * 8];
#pragma unroll
            for (int tn = 0; tn < 4; ++tn)
                bfr[tn] = *(const v8s*)&Bl[(wn * 64 + tn * 16 + r) * 72 + ks * 32 + qq * 8];
#pragma unroll
            for (int tm = 0; tm < 4; ++tm)
#pragma unroll
                for (int tn = 0; tn < 4; ++tn)
                    acc[tm][tn] = __builtin_amdgcn_mfma_f32_16x16x32_bf16(af[tm], bfr[tn], acc[tm][tn], 0, 0, 0);
        }
        __syncthreads();
    }
    int r = lane & 15, qq = lane >> 4;
#pragma unroll
    for (int tm = 0; tm < 4; ++tm)
#pragma unroll
        for (int tn = 0; tn < 4; ++tn) {
            int col = wn * 64 + tn * 16 + r;
            float bias = cbf[col];
#pragma unroll
            for (int reg = 0; reg < 4; ++reg) {
                int grow = m0 + wm * 64 + tm * 16 + qq * 4 + reg;
                if (grow < M) {
                    float v = acc[tm][tn][reg] + bias;
                    out[(size_t)grow * 128 + col] = fmaxf(v, 0.f);
                }
            }
        }
}

// ---------------- launch ----------------

extern "C" void kernel_launch(void* const* d_in, const int* in_sizes, int n_in,
                              void* d_out, int out_size, void* d_ws, size_t ws_size,
                              hipStream_t stream) {
    const float* x     = (const float*)d_in[0];
    const int*   e0    = (const int*)d_in[1];
    const int*   e1    = (const int*)d_in[2];
    const float* Wrel  = (const float*)d_in[3];
    const float* Wself = (const float*)d_in[4];
    const float* convw = (const float*)d_in[5];
    const float* convb = (const float*)d_in[6];
    float* out = (float*)d_out;

    int N = in_sizes[0] / 128;   // 100000
    int E = in_sizes[1] / 2;     // 600000
    int nbrr = (N + 255) >> 8;   // 391 buckets per relation
    int NB = 2 * nbrr;           // 782

    char* p = (char*)d_ws;
    auto alloc = [&](size_t bytes) { char* q = p; p += (bytes + 255) & ~(size_t)255; return q; };
    int*  gcnt  = (int*)alloc((size_t)MAXNB * 4);
    int*  gbase = (int*)alloc((size_t)(MAXNB + 1) * 4);
    int*  gcur  = (int*)alloc((size_t)MAXNB * 4);
    int*  flag  = (int*)alloc(256);
    unsigned int* esorted = (unsigned int*)alloc((size_t)2 * E * 4);
    int*  esrc  = (int*)alloc((size_t)2 * E * 4);
    int*  off   = (int*)alloc((size_t)2 * N * 4);
    int*  cnt   = (int*)alloc((size_t)2 * N * 4);
    bf16* Ab   = (bf16*)alloc((size_t)N * 384 * 2);   // [H0 | H1 | x_bf16]
    bf16* agg  = (bf16*)alloc((size_t)N * 128 * 2);
    bf16* B1T  = (bf16*)alloc(384 * 128 * 2);
    bf16* B2T  = (bf16*)alloc(384 * 128 * 2);
    float* cbf = (float*)alloc(512);

    hipMemsetAsync(gcnt, 0, (size_t)NB * 4, stream);

    detect_kernel<<<1, 256, 0, stream>>>(e0, flag, E);

    cvt_kernel<<<(N * 32 + 255) / 256, 256, 0, stream>>>((const float4*)x, (uint2*)Ab, N);

    int chBlocks = (2 * E + CH - 1) / CH;    // 147
    count_kernel<<<chBlocks, 256, 0, stream>>>(e0, e1, flag, gcnt, E, nbrr);
    bscan_kernel<<<1, 256, 0, stream>>>(gcnt, gbase, gcur, NB);
    dist_kernel<<<chBlocks, 256, 0, stream>>>(e0, e1, flag, gcur, esorted, E, nbrr);
    csr_kernel<<<NB, 256, 0, stream>>>(esorted, gbase, off, cnt, esrc, N, nbrr);

    gather_kernel<<<(2 * N + 7) / 8, 256, 0, stream>>>(off, cnt, esrc, (uint2*)Ab, N);

    prep_kernel<<<(98432 + 255) / 256, 256, 0, stream>>>(Wrel, Wself, convw, convb, B1T, B2T, cbf);

    int mBlocks = (N + 127) / 128;
    gemm1_kernel<<<mBlocks, 256, 0, stream>>>(Ab, B1T, agg, N);
    gemm2_kernel<<<mBlocks, 256, 0, stream>>>(agg, B2T, cbf, out, N);
}